// Round 7
// baseline (248.434 us; speedup 1.0000x reference)
//
#include <hip/hip_runtime.h>
#include <stdint.h>
#include <stddef.h>

#define Bn 32
#define Cc 512
#define Hh 40
#define Ww 40
#define Npix 1600
#define NCx 20
#define NCELL (Bn*Npix)      // 51200
#define CONF 0.3f
#define NMS_T 0.5f
#define NOUT 25

// k1 geometry: 64 cells/block (1 cell/lane), 4 waves split C, 25 tiles/image
#define CB 64
#define BPI 25               // 25*64 = 1600
#define NWAVE 4
#define CR (Cc/NWAVE)        // 128 channels per wave
#define FB 8                 // feat batch (double-buffered 2x8)

// workspace layout (float offsets)
#define WS_WT     0
#define WS_BOXES  (WS_WT + (size_t)NOUT*Cc)
#define WS_SCORES (WS_BOXES + (size_t)NCELL*4)
#define WS_LABELS (WS_SCORES + (size_t)NCELL)

__device__ __forceinline__ float sigmoidf_(float x) {
    return 1.0f / (1.0f + expf(-x));
}

// ---------------- Kernel 0: pack transposed weights Wt[o][c] ----------------
__global__ __launch_bounds__(64) void k0_pack(
    const float* __restrict__ w_obj, const float* __restrict__ w_cls,
    const float* __restrict__ w_reg, float* __restrict__ Wt)
{
    int c = blockIdx.x * 64 + threadIdx.x;
    if (c < Cc) {
        Wt[c] = w_obj[c];
        #pragma unroll
        for (int o = 0; o < NCx; ++o) Wt[(size_t)(1 + o) * Cc + c] = w_cls[o * Cc + c];
        #pragma unroll
        for (int o = 0; o < 4; ++o)   Wt[(size_t)(21 + o) * Cc + c] = w_reg[o * Cc + c];
    }
}

// load FB consecutive channels' feat value for this lane's cell
__device__ __forceinline__ void ld_batch(float dst[FB], const float* __restrict__ fp,
                                         int base) {
    #pragma unroll
    for (int t = 0; t < FB; ++t) dst[t] = fp[(size_t)(base + t) * Npix];
}

// consume FB channels: acc[o] += x[t] * Wt[o][cw0+base+t], t ascending
// (keeps every acc[o] chain strictly channel-ascending -> proven arithmetic)
__device__ __forceinline__ void fma_batch(float acc[NOUT], const float x[FB],
                                          const float* __restrict__ wt0, int base) {
    #pragma unroll
    for (int o = 0; o < NOUT; ++o) {
        const float* wr = wt0 + (size_t)o * Cc + base;   // uniform, 8 contiguous -> s_load_dwordx8
        #pragma unroll
        for (int t = 0; t < FB; ++t)
            acc[o] = fmaf(x[t], wr[t], acc[o]);
    }
}

// ---------------- Kernel 1: fused GEMM + reduce + decode + out-init ----------------
// block = 256 thr (4 waves). Wave w owns channels [w*128, w*128+128) for the
// block's 64 cells (1 cell/lane). Feat loads run in a 2x8 register double-buffer
// (8 independent dword loads always in flight under each 200-FMA block); weights
// come from the transposed Wt[o][c] via wave-uniform s_load_dwordx8.
// Sequential cross-wave combine -> bit-identical to R0/R3/R5/R6 decisions.
__global__ __launch_bounds__(256) void k1_fused(
    const float* __restrict__ feat, const float* __restrict__ Wt,
    const float* __restrict__ b_obj, const float* __restrict__ b_cls,
    const float* __restrict__ b_reg,
    float* __restrict__ out, float* __restrict__ ws_boxes,
    float* __restrict__ ws_scores, int* __restrict__ ws_labels)
{
    __shared__ float red[NWAVE][NOUT][CB];   // 25.6 KB, lane-stride-1 (conflict-free)

    const int tid = threadIdx.x;
    const int w   = __builtin_amdgcn_readfirstlane(tid >> 6);
    const int l   = tid & 63;
    const int b   = blockIdx.x / BPI;
    const int j   = blockIdx.x % BPI;
    const int n0  = j * CB;

    {
        const float* fp  = feat + (size_t)b * (Cc * Npix) + (size_t)(w * CR) * Npix + (n0 + l);
        const float* wt0 = Wt + w * CR;

        float acc[NOUT];
        #pragma unroll
        for (int o = 0; o < NOUT; ++o) acc[o] = 0.f;

        float xa[FB], xb[FB];
        ld_batch(xa, fp, 0);
        int base = 0;
        for (; base < CR - 2 * FB; base += 2 * FB) {
            ld_batch(xb, fp, base + FB);        // in flight under the next FMA block
            fma_batch(acc, xa, wt0, base);
            ld_batch(xa, fp, base + 2 * FB);
            fma_batch(acc, xb, wt0, base + FB);
        }
        // base == CR-16: last two batches, no further prefetch (no OOB reads)
        ld_batch(xb, fp, base + FB);
        fma_batch(acc, xa, wt0, base);
        fma_batch(acc, xb, wt0, base + FB);

        #pragma unroll
        for (int o = 0; o < NOUT; ++o) red[w][o][l] = acc[o];
    }
    __syncthreads();

    if (tid < CB) {
        float v[NOUT];
        // SEQUENTIAL combine (((w0+w1)+w2)+w3) — proven ordering.
        #pragma unroll
        for (int o = 0; o < NOUT; ++o) v[o] = red[0][o][tid];
        #pragma unroll
        for (int ch = 1; ch < NWAVE; ++ch) {
            #pragma unroll
            for (int o = 0; o < NOUT; ++o) v[o] += red[ch][o][tid];
        }

        float obj = v[0] + b_obj[0];
        float m = -1e30f; int label = 0;
        #pragma unroll
        for (int o = 0; o < NCx; ++o) {
            float cv = v[1 + o] + b_cls[o];
            if (cv > m) { m = cv; label = o; }   // strict > == first-max (argmax)
        }
        float r0 = v[21] + b_reg[0], r1 = v[22] + b_reg[1];
        float r2 = v[23] + b_reg[2], r3 = v[24] + b_reg[3];

        int n = n0 + tid;
        int g = b * Npix + n;
        int gy = n / Ww, gx = n % Ww;
        float cx = (sigmoidf_(r0) + (float)gx) * 32.0f;
        float cy = (sigmoidf_(r1) + (float)gy) * 32.0f;
        float bw = expf(r2) * 32.0f;
        float bh = expf(r3) * 32.0f;
        float x1 = cx - bw * 0.5f, y1 = cy - bh * 0.5f;
        float x2 = cx + bw * 0.5f, y2 = cy + bh * 0.5f;
        float score = sqrtf(sigmoidf_(obj) * sigmoidf_(m));

        ((float4*)ws_boxes)[g] = make_float4(x1, y1, x2, y2);
        ws_scores[g] = score;
        ws_labels[g] = label;

        float* orow = out + (size_t)g * 5;
        orow[0] = 0.f; orow[1] = 0.f; orow[2] = 0.f; orow[3] = 0.f; orow[4] = 0.f;
        out[(size_t)NCELL * 5 + g] = (float)label;
        out[(size_t)NCELL * 6 + g] = 0.f;
    }
}

// ---------------- Kernel 3: per-(image,class) greedy NMS (proven, unchanged) ----------------
#define KSUP 320
#define WUMAX ((KSUP + 31) / 32)   // 10

__global__ __launch_bounds__(256) void k3_nms(
    const float4* __restrict__ ws_boxes, const float* __restrict__ ws_scores,
    const int* __restrict__ ws_labels, float* __restrict__ out)
{
    __shared__ unsigned int cnt;
    __shared__ unsigned long long keys[2048];
    __shared__ float bx1[Npix], by1[Npix], bx2[Npix], by2[Npix], bar[Npix];
    __shared__ unsigned int sup[KSUP * WUMAX];   // reused as keep-flags later
    __shared__ unsigned int keepbits[WUMAX];

    const int tid = threadIdx.x;
    const int b   = blockIdx.x / NCx;
    const int cls = blockIdx.x % NCx;
    const int gbase = b * Npix;

    if (tid == 0) cnt = 0;
    __syncthreads();

    for (int n = tid; n < Npix; n += 256) {
        float s = ws_scores[gbase + n];
        if (s > CONF && ws_labels[gbase + n] == cls) {
            unsigned int pos = atomicAdd(&cnt, 1u);
            unsigned int sb = __float_as_uint(s);
            keys[pos] = ((unsigned long long)(~sb) << 32) | (unsigned int)n;
        }
    }
    __syncthreads();
    const int k = (int)cnt;
    if (k == 0) return;

    int M = 2; while (M < k) M <<= 1;
    for (int s = tid; s < M; s += 256) if (s >= k) keys[s] = ~0ull;
    __syncthreads();

    for (int sz = 2; sz <= M; sz <<= 1) {
        for (int st = sz >> 1; st > 0; st >>= 1) {
            for (int t = tid; t < M; t += 256) {
                int p = t ^ st;
                if (p > t) {
                    unsigned long long a = keys[t], c = keys[p];
                    bool up = ((t & sz) == 0);
                    if (up ? (a > c) : (a < c)) { keys[t] = c; keys[p] = a; }
                }
            }
            __syncthreads();
        }
    }

    for (int s = tid; s < k; s += 256) {
        int n = (int)(unsigned int)keys[s];
        float4 bx = ws_boxes[gbase + n];
        bx1[s] = bx.x; by1[s] = bx.y; bx2[s] = bx.z; by2[s] = bx.w;
        bar[s] = (bx.z - bx.x) * (bx.w - bx.y);
    }
    __syncthreads();

    if (k <= KSUP) {
        const int wu = (k + 31) >> 5;
        for (int t = tid; t < k * wu; t += 256) {
            int i = t / wu, w = t - (t / wu) * wu;
            unsigned int bits = 0;
            int j0 = w << 5;
            float xi1 = bx1[i], yi1 = by1[i], xi2 = bx2[i], yi2 = by2[i], ai = bar[i];
            for (int jj = 0; jj < 32; ++jj) {
                int j = j0 + jj;
                if (j > i && j < k) {
                    float xx1 = fmaxf(xi1, bx1[j]);
                    float yy1 = fmaxf(yi1, by1[j]);
                    float xx2 = fminf(xi2, bx2[j]);
                    float yy2 = fminf(yi2, by2[j]);
                    float inter = fmaxf(xx2 - xx1, 0.f) * fmaxf(yy2 - yy1, 0.f);
                    float uni = ai + bar[j] - inter;
                    if (inter / uni > NMS_T) bits |= (1u << jj);
                }
            }
            sup[i * wu + w] = bits;
        }
        if (tid < wu) {
            int rem = k - (tid << 5);
            keepbits[tid] = (rem >= 32) ? 0xFFFFFFFFu : ((1u << rem) - 1u);
        }
        __syncthreads();

        if (tid < 64) {
            for (int i = 0; i < k; ++i) {
                unsigned int cur = keepbits[i >> 5];
                if ((cur >> (i & 31)) & 1u) {
                    if (tid < wu) keepbits[tid] &= ~sup[i * wu + tid];
                }
            }
            unsigned int* keepF = sup;
            for (int s2 = tid; s2 < k; s2 += 64)
                keepF[s2] = (keepbits[s2 >> 5] >> (s2 & 31)) & 1u;
        }
        __syncthreads();
    } else {
        unsigned int* keepF = sup;
        for (int s = tid; s < k; s += 256) keepF[s] = 1u;
        __syncthreads();
        for (int i = 0; i < k; ++i) {
            __syncthreads();
            if (keepF[i]) {
                float xi1 = bx1[i], yi1 = by1[i], xi2 = bx2[i], yi2 = by2[i], ai = bar[i];
                for (int j = i + 1 + tid; j < k; j += 256) {
                    float xx1 = fmaxf(xi1, bx1[j]);
                    float yy1 = fmaxf(yi1, by1[j]);
                    float xx2 = fminf(xi2, bx2[j]);
                    float yy2 = fminf(yi2, by2[j]);
                    float inter = fmaxf(xx2 - xx1, 0.f) * fmaxf(yy2 - yy1, 0.f);
                    float uni = ai + bar[j] - inter;
                    if (inter / uni > NMS_T) keepF[j] = 0u;
                }
            }
        }
        __syncthreads();
    }

    unsigned int* keepF = sup;
    for (int s = tid; s < k; s += 256) {
        if (keepF[s]) {
            int n = (int)(unsigned int)keys[s];
            unsigned int sb = ~(unsigned int)(keys[s] >> 32);
            float sc = __uint_as_float(sb);
            float* orow = out + (size_t)(gbase + n) * 5;
            orow[0] = bx1[s]; orow[1] = by1[s];
            orow[2] = bx2[s]; orow[3] = by2[s];
            orow[4] = sc;
            out[(size_t)NCELL * 6 + gbase + n] = 1.0f;
        }
    }
}

extern "C" void kernel_launch(void* const* d_in, const int* in_sizes, int n_in,
                              void* d_out, int out_size, void* d_ws, size_t ws_size,
                              hipStream_t stream) {
    const float* feat  = (const float*)d_in[0];
    const float* w_obj = (const float*)d_in[1];
    const float* b_obj = (const float*)d_in[2];
    const float* w_cls = (const float*)d_in[3];
    const float* b_cls = (const float*)d_in[4];
    const float* w_reg = (const float*)d_in[5];
    const float* b_reg = (const float*)d_in[6];
    float* out = (float*)d_out;
    float* ws  = (float*)d_ws;

    float* Wt     = ws + WS_WT;
    float* boxes  = ws + WS_BOXES;
    float* scores = ws + WS_SCORES;
    int*   labels = (int*)(ws + WS_LABELS);

    k0_pack<<<(Cc + 63) / 64, 64, 0, stream>>>(w_obj, w_cls, w_reg, Wt);
    k1_fused<<<Bn * BPI, 256, 0, stream>>>(feat, Wt, b_obj, b_cls, b_reg,
                                           out, boxes, scores, labels);
    k3_nms<<<Bn * NCx, 256, 0, stream>>>((const float4*)boxes, scores, labels, out);
}

// Round 8
// 244.598 us; speedup vs baseline: 1.0157x; 1.0157x over previous
//
#include <hip/hip_runtime.h>
#include <stdint.h>
#include <stddef.h>

#define Bn 32
#define Cc 512
#define Hh 40
#define Ww 40
#define Npix 1600
#define NCx 20
#define NCELL (Bn*Npix)      // 51200
#define CONF 0.3f
#define NMS_T 0.5f
#define NOUT 25
#define NROW 28              // 25 real output rows + 3 zero pad (uniform 7/wave)

// k1 geometry: 64 cells/block (1 cell/lane), 4 waves split OUTPUTS (7 rows each)
#define CB 64
#define BPI 25               // 25*64 = 1600
#define NWAVE 4
#define OPW 7                // output rows per wave (28 = 4*7, rows 25..27 are zeros)
#define CHUNK 128            // proven summation chunk (4 chunks, sequential combine)
#define FB 8                 // feat batch (register double-buffer 2x8)

// workspace layout (float offsets)
#define WS_WT     0
#define WS_BOXES  (WS_WT + (size_t)NROW*Cc)
#define WS_SCORES (WS_BOXES + (size_t)NCELL*4)
#define WS_LABELS (WS_SCORES + (size_t)NCELL)

__device__ __forceinline__ float sigmoidf_(float x) {
    return 1.0f / (1.0f + expf(-x));
}

// ---------------- Kernel 0: pack transposed weights Wt[o][c], zero pad rows ----------------
__global__ __launch_bounds__(64) void k0_pack(
    const float* __restrict__ w_obj, const float* __restrict__ w_cls,
    const float* __restrict__ w_reg, float* __restrict__ Wt)
{
    int c = blockIdx.x * 64 + threadIdx.x;
    if (c < Cc) {
        Wt[c] = w_obj[c];
        #pragma unroll
        for (int o = 0; o < NCx; ++o) Wt[(size_t)(1 + o) * Cc + c] = w_cls[o * Cc + c];
        #pragma unroll
        for (int o = 0; o < 4; ++o)   Wt[(size_t)(21 + o) * Cc + c] = w_reg[o * Cc + c];
        #pragma unroll
        for (int o = 25; o < NROW; ++o) Wt[(size_t)o * Cc + c] = 0.f;   // pad rows
    }
}

__device__ __forceinline__ void ld8(float dst[FB], const float* __restrict__ fp, int base) {
    #pragma unroll
    for (int t = 0; t < FB; ++t) dst[t] = fp[(size_t)(base + t) * Npix];
}

// consume 8 channels for this wave's 7 output rows; 56 scalar dwords in flight
// (7 x s_load_dwordx8), channel index t ascending per acc -> proven chain order
__device__ __forceinline__ void fma7(float acc[OPW], const float x[FB],
                                     const float* __restrict__ wbase, int base) {
    #pragma unroll
    for (int t = 0; t < FB; ++t) {
        float xv = x[t];
        #pragma unroll
        for (int o = 0; o < OPW; ++o)
            acc[o] = fmaf(xv, wbase[(size_t)o * Cc + base + t], acc[o]);
    }
}

// ---------------- Kernel 1: fused GEMM + decode + out-init (output-split waves) ----------------
// block = 256 thr (4 waves). Wave w computes output rows [7w, 7w+7) over ALL 512
// channels for the block's 64 cells (1 cell/lane). Summation: 4 chunks of 128
// channels, each ascending, combined sequentially (((c0+c1)+c2)+c3) — value-
// identical to the proven R0/R3/R5 arithmetic. No cross-wave reduce needed.
__global__ __launch_bounds__(256) void k1_fused(
    const float* __restrict__ feat, const float* __restrict__ Wt,
    const float* __restrict__ b_obj, const float* __restrict__ b_cls,
    const float* __restrict__ b_reg,
    float* __restrict__ out, float* __restrict__ ws_boxes,
    float* __restrict__ ws_scores, int* __restrict__ ws_labels)
{
    __shared__ float red[NROW][CB];   // 7 KB, lane-stride-1 (conflict-free)

    const int tid = threadIdx.x;
    const int w   = __builtin_amdgcn_readfirstlane(tid >> 6);
    const int l   = tid & 63;
    const int b   = blockIdx.x / BPI;
    const int j   = blockIdx.x % BPI;
    const int n0  = j * CB;

    {
        const float* fp    = feat + (size_t)b * (Cc * Npix) + (n0 + l);
        const float* wbase = Wt + (size_t)(w * OPW) * Cc;   // uniform -> s_load path

        float tot[OPW];
        #pragma unroll
        for (int ch = 0; ch < Cc / CHUNK; ++ch) {
            const int c0 = ch * CHUNK;
            float acc[OPW];
            #pragma unroll
            for (int o = 0; o < OPW; ++o) acc[o] = 0.f;

            float xa[FB], xb[FB];
            ld8(xa, fp, c0);
            int base = c0;
            #pragma unroll
            for (int g = 0; g < CHUNK / (2 * FB) - 1; ++g) {   // 7 double-bodies
                ld8(xb, fp, base + FB);
                fma7(acc, xa, wbase, base);
                ld8(xa, fp, base + 2 * FB);
                fma7(acc, xb, wbase, base + FB);
                base += 2 * FB;
            }
            ld8(xb, fp, base + FB);            // last pair, no further prefetch
            fma7(acc, xa, wbase, base);
            fma7(acc, xb, wbase, base + FB);

            #pragma unroll
            for (int o = 0; o < OPW; ++o)
                tot[o] = (ch == 0) ? acc[o] : (tot[o] + acc[o]);   // sequential combine
        }
        #pragma unroll
        for (int o = 0; o < OPW; ++o) red[w * OPW + o][l] = tot[o];
    }
    __syncthreads();

    if (tid < CB) {
        float v[NOUT];
        #pragma unroll
        for (int o = 0; o < NOUT; ++o) v[o] = red[o][tid];

        float obj = v[0] + b_obj[0];
        float m = -1e30f; int label = 0;
        #pragma unroll
        for (int o = 0; o < NCx; ++o) {
            float cv = v[1 + o] + b_cls[o];
            if (cv > m) { m = cv; label = o; }   // strict > == first-max (argmax)
        }
        float r0 = v[21] + b_reg[0], r1 = v[22] + b_reg[1];
        float r2 = v[23] + b_reg[2], r3 = v[24] + b_reg[3];

        int n = n0 + tid;
        int g = b * Npix + n;
        int gy = n / Ww, gx = n % Ww;
        float cx = (sigmoidf_(r0) + (float)gx) * 32.0f;
        float cy = (sigmoidf_(r1) + (float)gy) * 32.0f;
        float bw = expf(r2) * 32.0f;
        float bh = expf(r3) * 32.0f;
        float x1 = cx - bw * 0.5f, y1 = cy - bh * 0.5f;
        float x2 = cx + bw * 0.5f, y2 = cy + bh * 0.5f;
        float score = sqrtf(sigmoidf_(obj) * sigmoidf_(m));

        ((float4*)ws_boxes)[g] = make_float4(x1, y1, x2, y2);
        ws_scores[g] = score;
        ws_labels[g] = label;

        float* orow = out + (size_t)g * 5;
        orow[0] = 0.f; orow[1] = 0.f; orow[2] = 0.f; orow[3] = 0.f; orow[4] = 0.f;
        out[(size_t)NCELL * 5 + g] = (float)label;
        out[(size_t)NCELL * 6 + g] = 0.f;
    }
}

// ---------------- Kernel 3: per-(image,class) greedy NMS (proven, unchanged) ----------------
#define KSUP 320
#define WUMAX ((KSUP + 31) / 32)   // 10

__global__ __launch_bounds__(256) void k3_nms(
    const float4* __restrict__ ws_boxes, const float* __restrict__ ws_scores,
    const int* __restrict__ ws_labels, float* __restrict__ out)
{
    __shared__ unsigned int cnt;
    __shared__ unsigned long long keys[2048];
    __shared__ float bx1[Npix], by1[Npix], bx2[Npix], by2[Npix], bar[Npix];
    __shared__ unsigned int sup[KSUP * WUMAX];   // reused as keep-flags later
    __shared__ unsigned int keepbits[WUMAX];

    const int tid = threadIdx.x;
    const int b   = blockIdx.x / NCx;
    const int cls = blockIdx.x % NCx;
    const int gbase = b * Npix;

    if (tid == 0) cnt = 0;
    __syncthreads();

    for (int n = tid; n < Npix; n += 256) {
        float s = ws_scores[gbase + n];
        if (s > CONF && ws_labels[gbase + n] == cls) {
            unsigned int pos = atomicAdd(&cnt, 1u);
            unsigned int sb = __float_as_uint(s);
            keys[pos] = ((unsigned long long)(~sb) << 32) | (unsigned int)n;
        }
    }
    __syncthreads();
    const int k = (int)cnt;
    if (k == 0) return;

    int M = 2; while (M < k) M <<= 1;
    for (int s = tid; s < M; s += 256) if (s >= k) keys[s] = ~0ull;
    __syncthreads();

    for (int sz = 2; sz <= M; sz <<= 1) {
        for (int st = sz >> 1; st > 0; st >>= 1) {
            for (int t = tid; t < M; t += 256) {
                int p = t ^ st;
                if (p > t) {
                    unsigned long long a = keys[t], c = keys[p];
                    bool up = ((t & sz) == 0);
                    if (up ? (a > c) : (a < c)) { keys[t] = c; keys[p] = a; }
                }
            }
            __syncthreads();
        }
    }

    for (int s = tid; s < k; s += 256) {
        int n = (int)(unsigned int)keys[s];
        float4 bx = ws_boxes[gbase + n];
        bx1[s] = bx.x; by1[s] = bx.y; bx2[s] = bx.z; by2[s] = bx.w;
        bar[s] = (bx.z - bx.x) * (bx.w - bx.y);
    }
    __syncthreads();

    if (k <= KSUP) {
        const int wu = (k + 31) >> 5;
        for (int t = tid; t < k * wu; t += 256) {
            int i = t / wu, w = t - (t / wu) * wu;
            unsigned int bits = 0;
            int j0 = w << 5;
            float xi1 = bx1[i], yi1 = by1[i], xi2 = bx2[i], yi2 = by2[i], ai = bar[i];
            for (int jj = 0; jj < 32; ++jj) {
                int j = j0 + jj;
                if (j > i && j < k) {
                    float xx1 = fmaxf(xi1, bx1[j]);
                    float yy1 = fmaxf(yi1, by1[j]);
                    float xx2 = fminf(xi2, bx2[j]);
                    float yy2 = fminf(yi2, by2[j]);
                    float inter = fmaxf(xx2 - xx1, 0.f) * fmaxf(yy2 - yy1, 0.f);
                    float uni = ai + bar[j] - inter;
                    if (inter / uni > NMS_T) bits |= (1u << jj);
                }
            }
            sup[i * wu + w] = bits;
        }
        if (tid < wu) {
            int rem = k - (tid << 5);
            keepbits[tid] = (rem >= 32) ? 0xFFFFFFFFu : ((1u << rem) - 1u);
        }
        __syncthreads();

        if (tid < 64) {
            for (int i = 0; i < k; ++i) {
                unsigned int cur = keepbits[i >> 5];
                if ((cur >> (i & 31)) & 1u) {
                    if (tid < wu) keepbits[tid] &= ~sup[i * wu + tid];
                }
            }
            unsigned int* keepF = sup;
            for (int s2 = tid; s2 < k; s2 += 64)
                keepF[s2] = (keepbits[s2 >> 5] >> (s2 & 31)) & 1u;
        }
        __syncthreads();
    } else {
        unsigned int* keepF = sup;
        for (int s = tid; s < k; s += 256) keepF[s] = 1u;
        __syncthreads();
        for (int i = 0; i < k; ++i) {
            __syncthreads();
            if (keepF[i]) {
                float xi1 = bx1[i], yi1 = by1[i], xi2 = bx2[i], yi2 = by2[i], ai = bar[i];
                for (int j = i + 1 + tid; j < k; j += 256) {
                    float xx1 = fmaxf(xi1, bx1[j]);
                    float yy1 = fmaxf(yi1, by1[j]);
                    float xx2 = fminf(xi2, bx2[j]);
                    float yy2 = fminf(yi2, by2[j]);
                    float inter = fmaxf(xx2 - xx1, 0.f) * fmaxf(yy2 - yy1, 0.f);
                    float uni = ai + bar[j] - inter;
                    if (inter / uni > NMS_T) keepF[j] = 0u;
                }
            }
        }
        __syncthreads();
    }

    unsigned int* keepF = sup;
    for (int s = tid; s < k; s += 256) {
        if (keepF[s]) {
            int n = (int)(unsigned int)keys[s];
            unsigned int sb = ~(unsigned int)(keys[s] >> 32);
            float sc = __uint_as_float(sb);
            float* orow = out + (size_t)(gbase + n) * 5;
            orow[0] = bx1[s]; orow[1] = by1[s];
            orow[2] = bx2[s]; orow[3] = by2[s];
            orow[4] = sc;
            out[(size_t)NCELL * 6 + gbase + n] = 1.0f;
        }
    }
}

extern "C" void kernel_launch(void* const* d_in, const int* in_sizes, int n_in,
                              void* d_out, int out_size, void* d_ws, size_t ws_size,
                              hipStream_t stream) {
    const float* feat  = (const float*)d_in[0];
    const float* w_obj = (const float*)d_in[1];
    const float* b_obj = (const float*)d_in[2];
    const float* w_cls = (const float*)d_in[3];
    const float* b_cls = (const float*)d_in[4];
    const float* w_reg = (const float*)d_in[5];
    const float* b_reg = (const float*)d_in[6];
    float* out = (float*)d_out;
    float* ws  = (float*)d_ws;

    float* Wt     = ws + WS_WT;
    float* boxes  = ws + WS_BOXES;
    float* scores = ws + WS_SCORES;
    int*   labels = (int*)(ws + WS_LABELS);

    k0_pack<<<(Cc + 63) / 64, 64, 0, stream>>>(w_obj, w_cls, w_reg, Wt);
    k1_fused<<<Bn * BPI, 256, 0, stream>>>(feat, Wt, b_obj, b_cls, b_reg,
                                           out, boxes, scores, labels);
    k3_nms<<<Bn * NCx, 256, 0, stream>>>((const float4*)boxes, scores, labels, out);
}

// Round 9
// 222.385 us; speedup vs baseline: 1.1171x; 1.0999x over previous
//
#include <hip/hip_runtime.h>
#include <stdint.h>
#include <stddef.h>

#define Bn 32
#define Cc 512
#define Hh 40
#define Ww 40
#define Npix 1600
#define NCx 20
#define NCELL (Bn*Npix)      // 51200
#define CONF 0.3f
#define NMS_T 0.5f
#define NOUT 25
#define WSTRIDE 28           // padded row (25 + 3 zeros), 112 B = 16B-aligned

// k1 geometry: 64 cells/block (1 cell/lane), 4 waves split C, 25 tiles/image
#define CB 64
#define BPI 25               // 25*64 = 1600
#define NWAVE 4
#define CR (Cc/NWAVE)        // 128 channels per wave
#define FB 8                 // feat register double-buffer 2x8

// workspace layout (float offsets)
#define WS_WPK    0
#define WS_BOXES  (WS_WPK + (size_t)Cc*WSTRIDE)
#define WS_SCORES (WS_BOXES + (size_t)NCELL*4)
#define WS_LABELS (WS_SCORES + (size_t)NCELL)

#define SMEM_FLOATS (Cc*WSTRIDE)   // 14336 floats = 57344 B (> red 6400 floats)

__device__ __forceinline__ float sigmoidf_(float x) {
    return 1.0f / (1.0f + expf(-x));
}

// ---------------- Kernel 0: pack weights into [c][28] rows (zero-padded) ----------------
__global__ __launch_bounds__(64) void k0_pack(
    const float* __restrict__ w_obj, const float* __restrict__ w_cls,
    const float* __restrict__ w_reg, float* __restrict__ Wpk)
{
    int c = blockIdx.x * 64 + threadIdx.x;
    if (c < Cc) {
        float* row = Wpk + (size_t)c * WSTRIDE;
        row[0] = w_obj[c];
        #pragma unroll
        for (int o = 0; o < NCx; ++o) row[1 + o] = w_cls[o * Cc + c];
        #pragma unroll
        for (int o = 0; o < 4; ++o)   row[21 + o] = w_reg[o * Cc + c];
        row[25] = 0.f; row[26] = 0.f; row[27] = 0.f;
    }
}

__device__ __forceinline__ void ld8(float dst[FB], const float* __restrict__ fp, int base) {
    #pragma unroll
    for (int t = 0; t < FB; ++t) dst[t] = fp[(size_t)(base + t) * Npix];
}

// consume FB channels; weights come from LDS rows (ds_read_b128 broadcast,
// lgkmcnt pipe — never touches the vmcnt feat queue). Channel t ascending per
// acc -> proven chain order.
__device__ __forceinline__ void fma8_lds(float acc[NOUT], const float x[FB],
                                         const float* __restrict__ wl, int base) {
    #pragma unroll
    for (int t = 0; t < FB; ++t) {
        const float4* wr = (const float4*)(wl + (size_t)(base + t) * WSTRIDE);
        float xv = x[t];
        float4 w0 = wr[0], w1 = wr[1], w2 = wr[2], w3 = wr[3], w4 = wr[4], w5 = wr[5];
        float4 w6 = wr[6];   // only .x real
        acc[0]  = fmaf(xv, w0.x, acc[0]);
        acc[1]  = fmaf(xv, w0.y, acc[1]);
        acc[2]  = fmaf(xv, w0.z, acc[2]);
        acc[3]  = fmaf(xv, w0.w, acc[3]);
        acc[4]  = fmaf(xv, w1.x, acc[4]);
        acc[5]  = fmaf(xv, w1.y, acc[5]);
        acc[6]  = fmaf(xv, w1.z, acc[6]);
        acc[7]  = fmaf(xv, w1.w, acc[7]);
        acc[8]  = fmaf(xv, w2.x, acc[8]);
        acc[9]  = fmaf(xv, w2.y, acc[9]);
        acc[10] = fmaf(xv, w2.z, acc[10]);
        acc[11] = fmaf(xv, w2.w, acc[11]);
        acc[12] = fmaf(xv, w3.x, acc[12]);
        acc[13] = fmaf(xv, w3.y, acc[13]);
        acc[14] = fmaf(xv, w3.z, acc[14]);
        acc[15] = fmaf(xv, w3.w, acc[15]);
        acc[16] = fmaf(xv, w4.x, acc[16]);
        acc[17] = fmaf(xv, w4.y, acc[17]);
        acc[18] = fmaf(xv, w4.z, acc[18]);
        acc[19] = fmaf(xv, w4.w, acc[19]);
        acc[20] = fmaf(xv, w5.x, acc[20]);
        acc[21] = fmaf(xv, w5.y, acc[21]);
        acc[22] = fmaf(xv, w5.z, acc[22]);
        acc[23] = fmaf(xv, w5.w, acc[23]);
        acc[24] = fmaf(xv, w6.x, acc[24]);
    }
}

// ---------------- Kernel 1: fused GEMM + reduce + decode + out-init ----------------
// 256 thr (4 waves). Wave w owns channels [128w,128w+128) for 64 cells (1/lane).
// Weights staged once into LDS [c][28]; per-channel 7x ds_read_b128 broadcast
// (lgkm pipe) overlaps the 25-FMA block while the vmcnt queue carries ONLY the
// 2x8 double-buffered feat loads. red[] reuses the same LDS after a barrier.
// Chain order: per-chunk cc ascending, cross-wave sequential -> bit-identical.
__global__ __launch_bounds__(256) void k1_fused(
    const float* __restrict__ feat, const float* __restrict__ Wpk,
    const float* __restrict__ b_obj, const float* __restrict__ b_cls,
    const float* __restrict__ b_reg,
    float* __restrict__ out, float* __restrict__ ws_boxes,
    float* __restrict__ ws_scores, int* __restrict__ ws_labels)
{
    __shared__ float smem[SMEM_FLOATS];   // 57344 B: weights, then reused as red[]

    const int tid = threadIdx.x;
    const int w   = __builtin_amdgcn_readfirstlane(tid >> 6);
    const int l   = tid & 63;
    const int b   = blockIdx.x / BPI;
    const int j   = blockIdx.x % BPI;
    const int n0  = j * CB;

    // stage all 512 weight rows (coalesced float4 copy, 14 per thread)
    {
        const float4* src = (const float4*)Wpk;
        float4* dst = (float4*)smem;
        #pragma unroll
        for (int i = 0; i < SMEM_FLOATS / 4 / 256; ++i)
            dst[tid + i * 256] = src[tid + i * 256];
    }
    __syncthreads();

    float acc[NOUT];
    #pragma unroll
    for (int o = 0; o < NOUT; ++o) acc[o] = 0.f;

    {
        const int c0 = w * CR;
        const float* fp = feat + (size_t)b * (Cc * Npix) + (size_t)c0 * Npix + (n0 + l);
        const float* wl = smem + (size_t)c0 * WSTRIDE;   // wave's 128 rows

        float xa[FB], xb[FB];
        ld8(xa, fp, 0);
        int base = 0;
        #pragma unroll
        for (int g = 0; g < CR / (2 * FB) - 1; ++g) {   // 7 double-bodies
            ld8(xb, fp, base + FB);
            fma8_lds(acc, xa, wl, base);
            ld8(xa, fp, base + 2 * FB);
            fma8_lds(acc, xb, wl, base + FB);
            base += 2 * FB;
        }
        ld8(xb, fp, base + FB);
        fma8_lds(acc, xa, wl, base);
        fma8_lds(acc, xb, wl, base + FB);
    }
    __syncthreads();   // all waves done reading weights before red[] overwrite

    {
        float* red = smem;   // red[w][o][l] = smem[(w*25+o)*64 + l], 6400 floats
        #pragma unroll
        for (int o = 0; o < NOUT; ++o) red[((w * NOUT) + o) * CB + l] = acc[o];
    }
    __syncthreads();

    if (tid < CB) {
        const float* red = smem;
        float v[NOUT];
        // SEQUENTIAL combine (((w0+w1)+w2)+w3) — proven ordering.
        #pragma unroll
        for (int o = 0; o < NOUT; ++o) v[o] = red[o * CB + tid];
        #pragma unroll
        for (int ch = 1; ch < NWAVE; ++ch) {
            #pragma unroll
            for (int o = 0; o < NOUT; ++o)
                v[o] += red[((ch * NOUT) + o) * CB + tid];
        }

        float obj = v[0] + b_obj[0];
        float m = -1e30f; int label = 0;
        #pragma unroll
        for (int o = 0; o < NCx; ++o) {
            float cv = v[1 + o] + b_cls[o];
            if (cv > m) { m = cv; label = o; }   // strict > == first-max (argmax)
        }
        float r0 = v[21] + b_reg[0], r1 = v[22] + b_reg[1];
        float r2 = v[23] + b_reg[2], r3 = v[24] + b_reg[3];

        int n = n0 + tid;
        int g = b * Npix + n;
        int gy = n / Ww, gx = n % Ww;
        float cx = (sigmoidf_(r0) + (float)gx) * 32.0f;
        float cy = (sigmoidf_(r1) + (float)gy) * 32.0f;
        float bw = expf(r2) * 32.0f;
        float bh = expf(r3) * 32.0f;
        float x1 = cx - bw * 0.5f, y1 = cy - bh * 0.5f;
        float x2 = cx + bw * 0.5f, y2 = cy + bh * 0.5f;
        float score = sqrtf(sigmoidf_(obj) * sigmoidf_(m));

        ((float4*)ws_boxes)[g] = make_float4(x1, y1, x2, y2);
        ws_scores[g] = score;
        ws_labels[g] = label;

        float* orow = out + (size_t)g * 5;
        orow[0] = 0.f; orow[1] = 0.f; orow[2] = 0.f; orow[3] = 0.f; orow[4] = 0.f;
        out[(size_t)NCELL * 5 + g] = (float)label;
        out[(size_t)NCELL * 6 + g] = 0.f;
    }
}

// ---------------- Kernel 3: per-(image,class) greedy NMS (proven, unchanged) ----------------
#define KSUP 320
#define WUMAX ((KSUP + 31) / 32)   // 10

__global__ __launch_bounds__(256) void k3_nms(
    const float4* __restrict__ ws_boxes, const float* __restrict__ ws_scores,
    const int* __restrict__ ws_labels, float* __restrict__ out)
{
    __shared__ unsigned int cnt;
    __shared__ unsigned long long keys[2048];
    __shared__ float bx1[Npix], by1[Npix], bx2[Npix], by2[Npix], bar[Npix];
    __shared__ unsigned int sup[KSUP * WUMAX];   // reused as keep-flags later
    __shared__ unsigned int keepbits[WUMAX];

    const int tid = threadIdx.x;
    const int b   = blockIdx.x / NCx;
    const int cls = blockIdx.x % NCx;
    const int gbase = b * Npix;

    if (tid == 0) cnt = 0;
    __syncthreads();

    for (int n = tid; n < Npix; n += 256) {
        float s = ws_scores[gbase + n];
        if (s > CONF && ws_labels[gbase + n] == cls) {
            unsigned int pos = atomicAdd(&cnt, 1u);
            unsigned int sb = __float_as_uint(s);
            keys[pos] = ((unsigned long long)(~sb) << 32) | (unsigned int)n;
        }
    }
    __syncthreads();
    const int k = (int)cnt;
    if (k == 0) return;

    int M = 2; while (M < k) M <<= 1;
    for (int s = tid; s < M; s += 256) if (s >= k) keys[s] = ~0ull;
    __syncthreads();

    for (int sz = 2; sz <= M; sz <<= 1) {
        for (int st = sz >> 1; st > 0; st >>= 1) {
            for (int t = tid; t < M; t += 256) {
                int p = t ^ st;
                if (p > t) {
                    unsigned long long a = keys[t], c = keys[p];
                    bool up = ((t & sz) == 0);
                    if (up ? (a > c) : (a < c)) { keys[t] = c; keys[p] = a; }
                }
            }
            __syncthreads();
        }
    }

    for (int s = tid; s < k; s += 256) {
        int n = (int)(unsigned int)keys[s];
        float4 bx = ws_boxes[gbase + n];
        bx1[s] = bx.x; by1[s] = bx.y; bx2[s] = bx.z; by2[s] = bx.w;
        bar[s] = (bx.z - bx.x) * (bx.w - bx.y);
    }
    __syncthreads();

    if (k <= KSUP) {
        const int wu = (k + 31) >> 5;
        for (int t = tid; t < k * wu; t += 256) {
            int i = t / wu, w = t - (t / wu) * wu;
            unsigned int bits = 0;
            int j0 = w << 5;
            float xi1 = bx1[i], yi1 = by1[i], xi2 = bx2[i], yi2 = by2[i], ai = bar[i];
            for (int jj = 0; jj < 32; ++jj) {
                int j = j0 + jj;
                if (j > i && j < k) {
                    float xx1 = fmaxf(xi1, bx1[j]);
                    float yy1 = fmaxf(yi1, by1[j]);
                    float xx2 = fminf(xi2, bx2[j]);
                    float yy2 = fminf(yi2, by2[j]);
                    float inter = fmaxf(xx2 - xx1, 0.f) * fmaxf(yy2 - yy1, 0.f);
                    float uni = ai + bar[j] - inter;
                    if (inter / uni > NMS_T) bits |= (1u << jj);
                }
            }
            sup[i * wu + w] = bits;
        }
        if (tid < wu) {
            int rem = k - (tid << 5);
            keepbits[tid] = (rem >= 32) ? 0xFFFFFFFFu : ((1u << rem) - 1u);
        }
        __syncthreads();

        if (tid < 64) {
            for (int i = 0; i < k; ++i) {
                unsigned int cur = keepbits[i >> 5];
                if ((cur >> (i & 31)) & 1u) {
                    if (tid < wu) keepbits[tid] &= ~sup[i * wu + tid];
                }
            }
            unsigned int* keepF = sup;
            for (int s2 = tid; s2 < k; s2 += 64)
                keepF[s2] = (keepbits[s2 >> 5] >> (s2 & 31)) & 1u;
        }
        __syncthreads();
    } else {
        unsigned int* keepF = sup;
        for (int s = tid; s < k; s += 256) keepF[s] = 1u;
        __syncthreads();
        for (int i = 0; i < k; ++i) {
            __syncthreads();
            if (keepF[i]) {
                float xi1 = bx1[i], yi1 = by1[i], xi2 = bx2[i], yi2 = by2[i], ai = bar[i];
                for (int j = i + 1 + tid; j < k; j += 256) {
                    float xx1 = fmaxf(xi1, bx1[j]);
                    float yy1 = fmaxf(yi1, by1[j]);
                    float xx2 = fminf(xi2, bx2[j]);
                    float yy2 = fminf(yi2, by2[j]);
                    float inter = fmaxf(xx2 - xx1, 0.f) * fmaxf(yy2 - yy1, 0.f);
                    float uni = ai + bar[j] - inter;
                    if (inter / uni > NMS_T) keepF[j] = 0u;
                }
            }
        }
        __syncthreads();
    }

    unsigned int* keepF = sup;
    for (int s = tid; s < k; s += 256) {
        if (keepF[s]) {
            int n = (int)(unsigned int)keys[s];
            unsigned int sb = ~(unsigned int)(keys[s] >> 32);
            float sc = __uint_as_float(sb);
            float* orow = out + (size_t)(gbase + n) * 5;
            orow[0] = bx1[s]; orow[1] = by1[s];
            orow[2] = bx2[s]; orow[3] = by2[s];
            orow[4] = sc;
            out[(size_t)NCELL * 6 + gbase + n] = 1.0f;
        }
    }
}

extern "C" void kernel_launch(void* const* d_in, const int* in_sizes, int n_in,
                              void* d_out, int out_size, void* d_ws, size_t ws_size,
                              hipStream_t stream) {
    const float* feat  = (const float*)d_in[0];
    const float* w_obj = (const float*)d_in[1];
    const float* b_obj = (const float*)d_in[2];
    const float* w_cls = (const float*)d_in[3];
    const float* b_cls = (const float*)d_in[4];
    const float* w_reg = (const float*)d_in[5];
    const float* b_reg = (const float*)d_in[6];
    float* out = (float*)d_out;
    float* ws  = (float*)d_ws;

    float* Wpk    = ws + WS_WPK;
    float* boxes  = ws + WS_BOXES;
    float* scores = ws + WS_SCORES;
    int*   labels = (int*)(ws + WS_LABELS);

    k0_pack<<<(Cc + 63) / 64, 64, 0, stream>>>(w_obj, w_cls, w_reg, Wpk);
    k1_fused<<<Bn * BPI, 256, 0, stream>>>(feat, Wpk, b_obj, b_cls, b_reg,
                                           out, boxes, scores, labels);
    k3_nms<<<Bn * NCx, 256, 0, stream>>>((const float4*)boxes, scores, labels, out);
}